// Round 5
// baseline (60.725 us; speedup 1.0000x reference)
//
#include <hip/hip_runtime.h>
#include <math.h>

#define BB 4
#define LL 5
#define CC 64
#define HH 128
#define WW 256
#define NTOT 16
#define CG 8              // channels per block
#define HB 4              // output rows per block
#define HW (HH * WW)
#define NHB (HH / HB)     // 32
#define NWG (BB * (CC / CG) * NHB)  // 1024

__global__ __launch_bounds__(256, 4) void maxfusion_kernel(
    const float* __restrict__ x,        // (NTOT, C, H, W)
    const int* __restrict__ record_len, // (B,)
    const float* __restrict__ t,        // (B, L, L, 4, 4)
    float* __restrict__ out)            // (B, C, H, W)
{
    // Balance-aware XCD swizzle: HW round-robins bid%8 across XCDs.
    // XCD x owns cg=x for ALL b -> per-XCD work = sum(record_len) = 16
    // agent-panels (perfectly balanced), and all fetches of channel-plane
    // group cg stay in one XCD's L2.
    const int cg = blockIdx.x % 8;
    const int i  = blockIdx.x / 8;      // 0..127, sequential per XCD
    const int b  = i / NHB;
    const int hb = i % NHB;
    const int h0 = hb * HB;
    const int w  = threadIdx.x;

    const int rl = record_len[b];
    int off = 0;
    #pragma unroll
    for (int j = 0; j < BB; ++j) off += (j < b) ? record_len[j] : 0;

    const float gx = -1.0f + 2.0f * (float)w / (float)(WW - 1);

    float maxv[HB][CG];
    #pragma unroll
    for (int hh = 0; hh < HB; ++hh)
        #pragma unroll
        for (int c = 0; c < CG; ++c) maxv[hh][c] = -INFINITY;

    for (int l = 0; l < rl; ++l) {
        // t[b, 0, l] — block-uniform: scalar loads + SGPR math.
        const float* tm = t + (size_t)((b * LL * LL + l) * 16);
        const float m00 = tm[0];
        const float m01 = tm[1] * ((float)HH / (float)WW);
        const float m02 = tm[3] * (2.0f / (0.8f * (float)WW));
        const float m10 = tm[4] * ((float)WW / (float)HH);
        const float m11 = tm[5];
        const float m12 = tm[7] * (2.0f / (0.8f * (float)HH));
        const float sx  = 0.5f * (float)(WW - 1);
        const float sy  = 0.5f * (float)(HH - 1);
        const float a00 = m00 * sx, a01 = m01 * sx, a02 = (m02 + 1.0f) * sx;
        const float a10 = m10 * sy, a11 = m11 * sy, a12 = (m12 + 1.0f) * sy;

        float wxa[HB], wxb[HB], wy0v[HB], wy1v[HB];
        int off0[HB], off1[HB];
        #pragma unroll
        for (int hh = 0; hh < HB; ++hh) {
            const float gy = -1.0f + 2.0f * (float)(h0 + hh) / (float)(HH - 1);
            const float ix = a00 * gx + a01 * gy + a02;
            const float iy = a10 * gx + a11 * gy + a12;

            const float x0f = floorf(ix), y0f = floorf(iy);
            const float wx1 = ix - x0f, wx0 = 1.0f - wx1;
            const float wy1 = iy - y0f, wy0 = 1.0f - wy1;
            const int x0 = (int)x0f, y0 = (int)y0f;

            const bool inx = (x0 >= 0) && (x0 <= WW - 2);
            wxa[hh] = inx ? wx0 : ((x0 == -1)     ? wx1 : 0.0f);
            wxb[hh] = inx ? wx1 : ((x0 == WW - 1) ? wx0 : 0.0f);
            wy0v[hh] = ((y0 >= 0)     && (y0 <= HH - 1))     ? wy0 : 0.0f;
            wy1v[hh] = ((y0 + 1 >= 0) && (y0 + 1 <= HH - 1)) ? wy1 : 0.0f;

            const int k  = min(max(x0, 0), WW - 2);
            const int r0 = min(max(y0,     0), HH - 1);
            const int r1 = min(max(y0 + 1, 0), HH - 1);
            off0[hh] = r0 * WW + k;
            off1[hh] = r1 * WW + k;
        }

        const int n = off + l;  // always valid: off + rl <= NTOT
        const float* base = x + ((size_t)n * CC + (size_t)cg * CG) * HW;

        #pragma unroll
        for (int c = 0; c < CG; ++c) {
            const float* p = base + (size_t)c * HW;
            #pragma unroll
            for (int hh = 0; hh < HB; ++hh) {
                const float2 q0 = *reinterpret_cast<const float2*>(p + off0[hh]);
                const float2 q1 = *reinterpret_cast<const float2*>(p + off1[hh]);
                const float t0 = q0.x * wxa[hh] + q0.y * wxb[hh];
                const float t1 = q1.x * wxa[hh] + q1.y * wxb[hh];
                const float v  = t0 * wy0v[hh] + t1 * wy1v[hh];
                maxv[hh][c] = fmaxf(maxv[hh][c], v);
            }
        }
    }

    float* ob = out + (((size_t)b * CC + (size_t)cg * CG) * HH + h0) * WW + w;
    #pragma unroll
    for (int c = 0; c < CG; ++c)
        #pragma unroll
        for (int hh = 0; hh < HB; ++hh)
            __builtin_nontemporal_store(maxv[hh][c],
                                        ob + (size_t)c * HW + (size_t)hh * WW);
}

extern "C" void kernel_launch(void* const* d_in, const int* in_sizes, int n_in,
                              void* d_out, int out_size, void* d_ws, size_t ws_size,
                              hipStream_t stream) {
    const float* x          = (const float*)d_in[0];
    const int*   record_len = (const int*)d_in[1];
    const float* t          = (const float*)d_in[2];
    float* out = (float*)d_out;

    maxfusion_kernel<<<NWG, 256, 0, stream>>>(x, record_len, t, out);
}

// Round 6
// 40.745 us; speedup vs baseline: 1.4904x; 1.4904x over previous
//
#include <hip/hip_runtime.h>
#include <math.h>

#define BB 4
#define LL 5
#define CC 64
#define HH 128
#define WW 256
#define NTOT 16
#define CG 8  // channels per block
#define HW (HH * WW)
#define NWG (BB * (CC / CG) * HH)  // 4096

__global__ __launch_bounds__(256) void maxfusion_kernel(
    const float* __restrict__ x,        // (NTOT, C, H, W)
    const int* __restrict__ record_len, // (B,)
    const float* __restrict__ t,        // (B, L, L, 4, 4)
    float* __restrict__ out)            // (B, C, H, W)
{
    // Balance-aware XCD swizzle. HW round-robins bid%8 across the 8 XCDs:
    //   xcd <- cg          (one channel-group per XCD, for ALL batches)
    //   idx = bid/8 walks h fastest, then b.
    // Per-XCD work = sum(record_len) = 16 agent-panels (balanced, unlike
    // the per-b split where XCDs did 3..5 panels), and all fetches of
    // channel-group cg stay in one XCD's L2, streaming in h-order so row
    // r at output-row h is L2-hot when output-row h+1 needs it.
    const int cg  = blockIdx.x % 8;
    const int idx = blockIdx.x / 8;   // 0..511, sequential per XCD
    const int h   = idx % HH;
    const int b   = idx / HH;
    const int w   = threadIdx.x;

    const int rl = record_len[b];
    int off = 0;
    #pragma unroll
    for (int j = 0; j < BB; ++j) off += (j < b) ? record_len[j] : 0;

    const float gx = -1.0f + 2.0f * (float)w / (float)(WW - 1);
    const float gy = -1.0f + 2.0f * (float)h / (float)(HH - 1);

    float maxv[CG];
    #pragma unroll
    for (int c = 0; c < CG; ++c) maxv[c] = -INFINITY;

    for (int l = 0; l < rl; ++l) {
        // t[b, 0, l] — block-uniform: scalar loads + SGPR math.
        const float* tm = t + (size_t)((b * LL * LL + l) * 16);
        const float m00 = tm[0];
        const float m01 = tm[1] * ((float)HH / (float)WW);
        const float m02 = tm[3] * (2.0f / (0.8f * (float)WW));
        const float m10 = tm[4] * ((float)WW / (float)HH);
        const float m11 = tm[5];
        const float m12 = tm[7] * (2.0f / (0.8f * (float)HH));
        const float sx  = 0.5f * (float)(WW - 1);
        const float sy  = 0.5f * (float)(HH - 1);
        const float a00 = m00 * sx, a01 = m01 * sx, a02 = (m02 + 1.0f) * sx;
        const float a10 = m10 * sy, a11 = m11 * sy, a12 = (m12 + 1.0f) * sy;

        const float ix = a00 * gx + a01 * gy + a02;
        const float iy = a10 * gx + a11 * gy + a12;

        const float x0f = floorf(ix), y0f = floorf(iy);
        const float wx1 = ix - x0f, wx0 = 1.0f - wx1;
        const float wy1 = iy - y0f, wy0 = 1.0f - wy1;
        const int x0 = (int)x0f, y0 = (int)y0f;

        const bool inx = (x0 >= 0) && (x0 <= WW - 2);
        const float wxa = inx ? wx0 : ((x0 == -1)     ? wx1 : 0.0f);
        const float wxb = inx ? wx1 : ((x0 == WW - 1) ? wx0 : 0.0f);
        const float wy0v = ((y0 >= 0)     && (y0 <= HH - 1))     ? wy0 : 0.0f;
        const float wy1v = ((y0 + 1 >= 0) && (y0 + 1 <= HH - 1)) ? wy1 : 0.0f;

        const int k  = min(max(x0, 0), WW - 2);
        const int r0 = min(max(y0,     0), HH - 1);
        const int r1 = min(max(y0 + 1, 0), HH - 1);
        const int off0 = r0 * WW + k;
        const int off1 = r1 * WW + k;

        const int n = off + l;  // always valid: off + rl <= NTOT
        const float* base = x + ((size_t)n * CC + (size_t)cg * CG) * HW;

        #pragma unroll
        for (int c = 0; c < CG; ++c) {
            const float* p = base + (size_t)c * HW;
            const float2 q0 = *reinterpret_cast<const float2*>(p + off0);
            const float2 q1 = *reinterpret_cast<const float2*>(p + off1);
            const float t0 = q0.x * wxa + q0.y * wxb;
            const float t1 = q1.x * wxa + q1.y * wxb;
            const float v  = t0 * wy0v + t1 * wy1v;
            maxv[c] = fmaxf(maxv[c], v);
        }
    }

    float* ob = out + (((size_t)b * CC + (size_t)cg * CG) * HH + h) * WW + w;
    #pragma unroll
    for (int c = 0; c < CG; ++c)
        __builtin_nontemporal_store(maxv[c], ob + (size_t)c * HW);
}

extern "C" void kernel_launch(void* const* d_in, const int* in_sizes, int n_in,
                              void* d_out, int out_size, void* d_ws, size_t ws_size,
                              hipStream_t stream) {
    const float* x          = (const float*)d_in[0];
    const int*   record_len = (const int*)d_in[1];
    const float* t          = (const float*)d_in[2];
    float* out = (float*)d_out;

    maxfusion_kernel<<<NWG, 256, 0, stream>>>(x, record_len, t, out);
}